// Round 6
// baseline (461.937 us; speedup 1.0000x reference)
//
#include <hip/hip_runtime.h>

#define NPOINTS 262144
#define SUMH 224
#define SUMW 221
#define NREG 500
#define CPB 16           // chunks (of 64 points) per region — capacity 1024 >> max bin (~640)

// ---------- DPP helpers ----------
__device__ __forceinline__ float rlane(float v, int l) {
  return __int_as_float(__builtin_amdgcn_readlane(__float_as_int(v), l));
}
template<int CTRL>
__device__ __forceinline__ float dpp0(float x) {   // 0-fill on invalid
  return __int_as_float(__builtin_amdgcn_update_dpp(0, __float_as_int(x), CTRL, 0xF, 0xF, true));
}
template<int CTRL, int RM>
__device__ __forceinline__ float dpp_rm(float x) { // row-masked, old=0
  return __int_as_float(__builtin_amdgcn_update_dpp(0, __float_as_int(x), CTRL, RM, 0xF, false));
}
template<int CTRL>
__device__ __forceinline__ float dpp_max_(float x) {
  return fmaxf(x, __int_as_float(__builtin_amdgcn_update_dpp(__float_as_int(x), __float_as_int(x), CTRL, 0xF, 0xF, false)));
}
// 64-lane reduce / scan (region kernel)
__device__ __forceinline__ float wave_sum(float x) {
  x += dpp0<0x111>(x); x += dpp0<0x112>(x); x += dpp0<0x114>(x); x += dpp0<0x118>(x);
  x += dpp_rm<0x142, 0xA>(x); x += dpp_rm<0x143, 0xC>(x);
  return rlane(x, 63);
}
__device__ __forceinline__ float wave_max(float x) {
  x = dpp_max_<0x111>(x); x = dpp_max_<0x112>(x); x = dpp_max_<0x114>(x);
  x = dpp_max_<0x118>(x); x = dpp_max_<0x142>(x); x = dpp_max_<0x143>(x);
  return rlane(x, 63);
}
__device__ __forceinline__ float wave_scan_incl(float x) {
  x += dpp0<0x111>(x); x += dpp0<0x112>(x); x += dpp0<0x114>(x); x += dpp0<0x118>(x);
  x += dpp_rm<0x142, 0xA>(x);   // row_bcast:15 -> rows 1,3
  x += dpp_rm<0x143, 0xC>(x);   // row_bcast:31 -> rows 2,3
  return x;
}
// 16-lane group sum butterfly (serves 4 groups per wave simultaneously)
__device__ __forceinline__ float grp_sum(float x) {
  x += dpp0<0xB1>(x);    // quad_perm xor1
  x += dpp0<0x4E>(x);    // quad_perm xor2
  x += dpp0<0x141>(x);   // row_half_mirror
  x += dpp0<0x140>(x);   // row_mirror
  return x;
}

// ---------- Kernel: per-ROI tables ----------
// Per rix (stride SUMH floats), level slots {0..127, 128..191, 192..223}:
//   BL[j] = bin edge j (BL[0]=0, BL[n-1]=1)
//   HW[j] = 0.5*w_j                (0 for j=n-1)
//   HS[j] = 0.5*(w_{j-1} + w_j)    (trapezoid weight; w_{-1}=w_{n-1}=0)
template<int M, int SRC, int DST, int NB>
__device__ __forceinline__ void region_level(const float* __restrict__ wrow,
    float* __restrict__ BL, float* __restrict__ HW, float* __restrict__ HS,
    int lane, float* lds)
{
  float v0 = (lane < M) ? wrow[SRC + lane] : -1e30f;
  float v1 = -1e30f;
  if constexpr (NB == 128) { if (lane + 64 < M) v1 = wrow[SRC + lane + 64]; }
  float m = wave_max(fmaxf(v0, v1));
  float e0 = __expf(v0 - m);                 // 0 for padded slots
  float e1 = (NB == 128) ? __expf(v1 - m) : 0.0f;
  float sm = wave_sum(e0 + e1);
  float inv = 1.0f / sm;
  if (lane < NB) lds[lane] = e0;
  if constexpr (NB == 128) lds[lane + 64] = e1;
  __syncthreads();
  if (lane < NB) {
    HW[DST + lane] = 0.5f * e0 * inv;
    float prev = (lane == 0) ? 0.0f : lds[lane - 1];
    HS[DST + lane] = 0.5f * (e0 + prev) * inv;
  }
  if constexpr (NB == 128) {
    HW[DST + lane + 64] = 0.5f * e1 * inv;
    HS[DST + lane + 64] = 0.5f * (e1 + lds[lane + 63]) * inv;
  }
  float incl0 = wave_scan_incl(e0);
  if (lane == 0) BL[DST] = 0.0f;
  if (lane < M) BL[DST + 1 + lane] = (lane == M - 1) ? 1.0f : incl0 * inv;
  if constexpr (NB == 128) {
    float incl1 = wave_scan_incl(e1) + rlane(incl0, 63);
    int k = 64 + lane;
    if (k < M) BL[DST + 1 + k] = (k == M - 1) ? 1.0f : incl1 * inv;
  }
  __syncthreads();
}

__global__ void __launch_bounds__(64) region_kernel(
    const int* __restrict__ roi, const float* __restrict__ wemb,
    float* __restrict__ wsBL, float* __restrict__ wsHW, float* __restrict__ wsHS)
{
  __shared__ float lds[128];
  int rix = blockIdx.x;
  int lane = threadIdx.x;
  int greg = roi[rix];
  const float* wrow = wemb + (size_t)greg * SUMW;
  float* BL = wsBL + (size_t)rix * SUMH;
  float* HW = wsHW + (size_t)rix * SUMH;
  float* HS = wsHS + (size_t)rix * SUMH;
  region_level<127,   0,   0, 128>(wrow, BL, HW, HS, lane, lds);
  region_level< 63, 127, 128,  64>(wrow, BL, HW, HS, lane, lds);
  region_level< 31, 190, 192,  32>(wrow, BL, HW, HS, lane, lds);
}

// ---------- counting sort: zero -> LDS hist -> scan -> scatter ----------
__global__ void __launch_bounds__(512) zero_kernel(int* __restrict__ hist) {
  hist[threadIdx.x] = 0;
}

__global__ void __launch_bounds__(256) hist_kernel(
    const int* __restrict__ lix, int* __restrict__ hist)
{
  __shared__ int h[512];
  for (int i = threadIdx.x; i < 512; i += 256) h[i] = 0;
  __syncthreads();
  int base = blockIdx.x * 4096;
#pragma unroll
  for (int k = 0; k < 16; ++k) {
    int p = base + k * 256 + threadIdx.x;
    atomicAdd(&h[lix[p]], 1);
  }
  __syncthreads();
  for (int i = threadIdx.x; i < 500; i += 256) {
    int v = h[i];
    if (v) atomicAdd(&hist[i], v);
  }
}

__global__ void __launch_bounds__(512) scan_kernel(
    const int* __restrict__ hist, int* __restrict__ offs, int* __restrict__ cursor)
{
  __shared__ int sb[512];
  int t = threadIdx.x;
  int v = (t < NREG) ? hist[t] : 0;
  sb[t] = v;
  __syncthreads();
  for (int d = 1; d < 512; d <<= 1) {
    int add = (t >= d) ? sb[t - d] : 0;
    __syncthreads();
    sb[t] += add;
    __syncthreads();
  }
  if (t < NREG) {
    int excl = sb[t] - v;
    offs[t] = excl;
    cursor[t] = excl;
  }
}

__global__ void __launch_bounds__(256) scatter_kernel(
    const int* __restrict__ lix, int* __restrict__ cursor, int* __restrict__ sorted)
{
  int p = blockIdx.x * 256 + threadIdx.x;
  int r = lix[p];
  int slot = atomicAdd(&cursor[r], 1);
  sorted[slot] = p;
}

// ---------- spline kernel: block = one region-chunk; tables in registers ----------

template<int C>
__device__ __forceinline__ void apply16(float& xv, float& logdet, int s,
    const float (&u)[C], const float (&d)[C], const float (&bl)[C],
    const float (&hw)[C], const float (&hs)[C])
{
  float he[C], t[C], f[C];
#pragma unroll
  for (int i = 0; i < C; ++i) { he[i] = __expf(u[i] + d[i]); t[i] = he[i] * hs[i]; }
#pragma unroll
  for (int i = 0; i < C; ++i) f[i] = (bl[i] < xv) ? 1.0f : 0.0f;
  if (s == 0)  f[0]     = 1.0f;   // edge 0 always counted (clamp-low)
  if (s == 15) f[C - 1] = 0.0f;   // last edge never counted (clamp-high)
  float fN  = dpp0<0x101>(f[0]);   // row_shl:1 — next lane's first, 0 at lane 15 (masked anyway)
  float heN = dpp0<0x101>(he[0]);
  float area = 0.0f, hl = 0.0f, hr = 0.0f, loc = 0.0f, hwm = 0.0f, pt = 0.0f;
#pragma unroll
  for (int i = 0; i < C; ++i) {
    float fnext  = (i < C - 1) ? f[i + 1]  : fN;
    float henext = (i < C - 1) ? he[i + 1] : heN;
    float mi = f[i] * (1.0f - fnext);   // one-hot at bin bi
    area += t[i];
    hl  += he[i] * mi;
    hr  += henext * mi;
    loc += bl[i] * mi;
    hwm += hw[i] * mi;
    pt  += t[i] * f[i];                 // inclusive trapezoid sum through bi
  }
  area = grp_sum(area);
  hl  = grp_sum(hl);
  hr  = grp_sum(hr);
  loc = grp_sum(loc);
  hwm = grp_sum(hwm);
  pt  = grp_sum(pt);
  float larea = __log2f(area);
  float invarea = __builtin_amdgcn_rcpf(area);
  float part = pt - hl * hwm;           // unnormalized cdf at left edge of bin
  float inw = 2.0f * hwm;
  float alpha = (xv - loc) * __builtin_amdgcn_rcpf(inw);
  float dh = hr - hl;
  xv = ((0.5f * dh * alpha + hl) * alpha * inw + part) * invarea;
  logdet += (__log2f(alpha * dh + hl) - larea) * 0.69314718055994531f;
}

__device__ __forceinline__ void ld8(float (&a)[8], const float* p) {
  float4 q0 = *(const float4*)(p);
  float4 q1 = *(const float4*)(p + 4);
  a[0]=q0.x; a[1]=q0.y; a[2]=q0.z; a[3]=q0.w;
  a[4]=q1.x; a[5]=q1.y; a[6]=q1.z; a[7]=q1.w;
}
__device__ __forceinline__ void ld4(float (&a)[4], const float* p) {
  float4 q = *(const float4*)(p);
  a[0]=q.x; a[1]=q.y; a[2]=q.z; a[3]=q.w;
}
__device__ __forceinline__ void ld2(float (&a)[2], const float* p) {
  float2 q = *(const float2*)(p);
  a[0]=q.x; a[1]=q.y;
}

__global__ void __launch_bounds__(256, 4) spline_kernel(
    const float* __restrict__ x, const int* __restrict__ roi,
    const float* __restrict__ delta, const float* __restrict__ hemb,
    const float* __restrict__ wsBL, const float* __restrict__ wsHW,
    const float* __restrict__ wsHS, const int* __restrict__ hist,
    const int* __restrict__ offs, const int* __restrict__ sorted,
    float* __restrict__ out)
{
  int region = blockIdx.x / CPB;
  int chunk  = blockIdx.x % CPB;
  int cnt = hist[region];
  if (chunk * 64 >= cnt) return;       // block-uniform early exit (no LDS, no barriers)
  int base  = offs[region] + chunk * 64;
  int lastv = offs[region] + cnt - 1;

  int lane = (int)(threadIdx.x & 63);
  int wv   = (int)(threadIdx.x >> 6);
  int grp  = lane >> 4;
  int s    = lane & 15;

  int greg = roi[region];
  const float* Ur  = hemb + (size_t)greg  * SUMH;
  const float* BLr = wsBL + (size_t)region * SUMH;
  const float* HWr = wsHW + (size_t)region * SUMH;
  const float* HSr = wsHS + (size_t)region * SUMH;

  // block-uniform tables -> per-lane registers, loaded ONCE per block
  float u0[8], bl0[8], hw0[8], hs0[8];
  float u1[4], bl1[4], hw1[4], hs1[4];
  float u2[2], bl2[2], hw2[2], hs2[2];
  ld8(u0, Ur + 8 * s);         ld8(bl0, BLr + 8 * s);
  ld8(hw0, HWr + 8 * s);       ld8(hs0, HSr + 8 * s);
  ld4(u1, Ur + 128 + 4 * s);   ld4(bl1, BLr + 128 + 4 * s);
  ld4(hw1, HWr + 128 + 4 * s); ld4(hs1, HSr + 128 + 4 * s);
  ld2(u2, Ur + 192 + 2 * s);   ld2(bl2, BLr + 192 + 2 * s);
  ld2(hw2, HWr + 192 + 2 * s); ld2(hs2, HSr + 192 + 2 * s);

  // prefetch first iteration's point id
  int idx = base + wv * 4 + grp;
  int idxc = min(idx, lastv);
  int pid = sorted[idxc];

#pragma unroll
  for (int it = 0; it < 4; ++it) {
    bool valid = idx <= lastv;
    float xv = x[pid];
    const float* D = delta + (size_t)pid * SUMH;
    float d0[8], d1[4], d2[2];
    ld8(d0, D + 8 * s);
    ld4(d1, D + 128 + 4 * s);
    ld2(d2, D + 192 + 2 * s);

    // prefetch next iteration's pid (breaks the sorted->delta chained latency)
    int nidx = idx + 16;
    int pid_n = sorted[min(nidx, lastv)];

    float logdet = 0.0f;
    apply16<8>(xv, logdet, s, u0, d0, bl0, hw0, hs0);
    apply16<4>(xv, logdet, s, u1, d1, bl1, hw1, hs1);
    apply16<2>(xv, logdet, s, u2, d2, bl2, hw2, hs2);

    if (valid && s == 0) {
      out[pid] = xv;
      out[NPOINTS + pid] = logdet;
    }
    idx = nidx;
    pid = pid_n;
  }
}

// ---------- launch ----------

extern "C" void kernel_launch(void* const* d_in, const int* in_sizes, int n_in,
                              void* d_out, int out_size, void* d_ws, size_t ws_size,
                              hipStream_t stream) {
  const float* x     = (const float*)d_in[0];
  const int*   roi   = (const int*)  d_in[1];
  const int*   lix   = (const int*)  d_in[2];
  const float* delta = (const float*)d_in[3];
  const float* hemb  = (const float*)d_in[4];
  const float* wemb  = (const float*)d_in[5];

  float* wsBL = (float*)d_ws;                    // [500][224]
  float* wsHW = wsBL + (size_t)NREG * SUMH;      // [500][224]
  float* wsHS = wsHW + (size_t)NREG * SUMH;      // [500][224]
  int*   hist   = (int*)(wsHS + (size_t)NREG * SUMH);   // [512]
  int*   offs   = hist + 512;                           // [512]
  int*   cursor = offs + 512;                           // [512]
  int*   sorted = cursor + 512;                         // [262144]

  zero_kernel<<<1, 512, 0, stream>>>(hist);
  hist_kernel<<<NPOINTS / 4096, 256, 0, stream>>>(lix, hist);
  region_kernel<<<NREG, 64, 0, stream>>>(roi, wemb, wsBL, wsHW, wsHS);
  scan_kernel<<<1, 512, 0, stream>>>(hist, offs, cursor);
  scatter_kernel<<<NPOINTS / 256, 256, 0, stream>>>(lix, cursor, sorted);
  spline_kernel<<<NREG * CPB, 256, 0, stream>>>(x, roi, delta, hemb,
                                                wsBL, wsHW, wsHS,
                                                hist, offs, sorted, (float*)d_out);
}

// Round 7
// 347.037 us; speedup vs baseline: 1.3311x; 1.3311x over previous
//
#include <hip/hip_runtime.h>

#define NPOINTS 262144
#define SUMH 224
#define SUMW 221
#define NREG 500

// ---------- DPP helpers ----------
__device__ __forceinline__ float rlane(float v, int l) {
  return __int_as_float(__builtin_amdgcn_readlane(__float_as_int(v), l));
}
template<int CTRL>
__device__ __forceinline__ float dpp0(float x) {   // 0-fill on invalid
  return __int_as_float(__builtin_amdgcn_update_dpp(0, __float_as_int(x), CTRL, 0xF, 0xF, true));
}
template<int CTRL, int RM>
__device__ __forceinline__ float dpp_rm(float x) { // row-masked, old=0
  return __int_as_float(__builtin_amdgcn_update_dpp(0, __float_as_int(x), CTRL, RM, 0xF, false));
}
template<int CTRL>
__device__ __forceinline__ float dpp_max_(float x) {
  return fmaxf(x, __int_as_float(__builtin_amdgcn_update_dpp(__float_as_int(x), __float_as_int(x), CTRL, 0xF, 0xF, false)));
}
// 64-lane reduce / scan (region kernel)
__device__ __forceinline__ float wave_sum(float x) {
  x += dpp0<0x111>(x); x += dpp0<0x112>(x); x += dpp0<0x114>(x); x += dpp0<0x118>(x);
  x += dpp_rm<0x142, 0xA>(x); x += dpp_rm<0x143, 0xC>(x);
  return rlane(x, 63);
}
__device__ __forceinline__ float wave_max(float x) {
  x = dpp_max_<0x111>(x); x = dpp_max_<0x112>(x); x = dpp_max_<0x114>(x);
  x = dpp_max_<0x118>(x); x = dpp_max_<0x142>(x); x = dpp_max_<0x143>(x);
  return rlane(x, 63);
}
__device__ __forceinline__ float wave_scan_incl(float x) {
  x += dpp0<0x111>(x); x += dpp0<0x112>(x); x += dpp0<0x114>(x); x += dpp0<0x118>(x);
  x += dpp_rm<0x142, 0xA>(x);   // row_bcast:15 -> rows 1,3
  x += dpp_rm<0x143, 0xC>(x);   // row_bcast:31 -> rows 2,3
  return x;
}
// 32-lane group sum: 16-lane DPP butterfly + xor16 via ds_swizzle
__device__ __forceinline__ float grp32_sum(float x) {
  x += dpp0<0xB1>(x);    // xor1
  x += dpp0<0x4E>(x);    // xor2
  x += dpp0<0x141>(x);   // row_half_mirror
  x += dpp0<0x140>(x);   // row_mirror
  x += __int_as_float(__builtin_amdgcn_ds_swizzle(__float_as_int(x), 0x401F)); // xor16
  return x;
}
__device__ __forceinline__ float bperm(int byteidx, float v) {
  return __int_as_float(__builtin_amdgcn_ds_bpermute(byteidx, __float_as_int(v)));
}

// ---------- Kernel 1: per-ROI tables ----------
// Per rix (stride SUMH floats), level slots {0..127, 128..191, 192..223}:
//   BL[j] = bin edge j (BL[0]=0, BL[n-1]=1)
//   HW[j] = 0.5*w_j                (0 for j=n-1)
//   HS[j] = 0.5*(w_{j-1} + w_j)    (trapezoid weight; w_{-1}=w_{n-1}=0)
template<int M, int SRC, int DST, int NB>
__device__ __forceinline__ void region_level(const float* __restrict__ wrow,
    float* __restrict__ BL, float* __restrict__ HW, float* __restrict__ HS,
    int lane, float* lds)
{
  float v0 = (lane < M) ? wrow[SRC + lane] : -1e30f;
  float v1 = -1e30f;
  if constexpr (NB == 128) { if (lane + 64 < M) v1 = wrow[SRC + lane + 64]; }
  float m = wave_max(fmaxf(v0, v1));
  float e0 = __expf(v0 - m);                 // 0 for padded slots
  float e1 = (NB == 128) ? __expf(v1 - m) : 0.0f;
  float sm = wave_sum(e0 + e1);
  float inv = 1.0f / sm;
  if (lane < NB) lds[lane] = e0;
  if constexpr (NB == 128) lds[lane + 64] = e1;
  __syncthreads();
  if (lane < NB) {
    HW[DST + lane] = 0.5f * e0 * inv;
    float prev = (lane == 0) ? 0.0f : lds[lane - 1];
    HS[DST + lane] = 0.5f * (e0 + prev) * inv;
  }
  if constexpr (NB == 128) {
    HW[DST + lane + 64] = 0.5f * e1 * inv;
    HS[DST + lane + 64] = 0.5f * (e1 + lds[lane + 63]) * inv;
  }
  float incl0 = wave_scan_incl(e0);
  if (lane == 0) BL[DST] = 0.0f;
  if (lane < M) BL[DST + 1 + lane] = (lane == M - 1) ? 1.0f : incl0 * inv;
  if constexpr (NB == 128) {
    float incl1 = wave_scan_incl(e1) + rlane(incl0, 63);
    int k = 64 + lane;
    if (k < M) BL[DST + 1 + k] = (k == M - 1) ? 1.0f : incl1 * inv;
  }
  __syncthreads();
}

__global__ void __launch_bounds__(64) region_kernel(
    const int* __restrict__ roi, const float* __restrict__ wemb,
    float* __restrict__ wsBL, float* __restrict__ wsHW, float* __restrict__ wsHS)
{
  __shared__ float lds[128];
  int rix = blockIdx.x;
  int lane = threadIdx.x;
  int greg = roi[rix];
  const float* wrow = wemb + (size_t)greg * SUMW;
  float* BL = wsBL + (size_t)rix * SUMH;
  float* HW = wsHW + (size_t)rix * SUMH;
  float* HS = wsHS + (size_t)rix * SUMH;
  region_level<127,   0,   0, 128>(wrow, BL, HW, HS, lane, lds);
  region_level< 63, 127, 128,  64>(wrow, BL, HW, HS, lane, lds);
  region_level< 31, 190, 192,  32>(wrow, BL, HW, HS, lane, lds);
}

// ---------- Kernel 2: 32-lane groups, 2-deep point pipeline (4 pts/wave) ----------

struct PtState {
  float4 a0, b0, e0, f0, g0;   // level0 (C=4): u, d, bl, hw, hs
  float2 a1, b1, e1, f1, g1;   // level1 (C=2)
  float  a2, b2, e2, f2, g2;   // level2 (C=1)
  float  xv;
  int    pid;
};

__device__ __forceinline__ void load_pt(PtState& P, int pid, int s,
    const float* __restrict__ x, const int* __restrict__ lix,
    const int* __restrict__ roi, const float* __restrict__ delta,
    const float* __restrict__ hemb, const float* __restrict__ wsBL,
    const float* __restrict__ wsHW, const float* __restrict__ wsHS)
{
  P.pid = pid;
  P.xv = x[pid];
  int r = lix[pid];
  int greg = roi[r];
  const float* U  = hemb + (size_t)greg * SUMH;
  const float* D  = delta + (size_t)pid * SUMH;
  const float* BL = wsBL + (size_t)r * SUMH;
  const float* HW = wsHW + (size_t)r * SUMH;
  const float* HS = wsHS + (size_t)r * SUMH;
  int c0 = s * 4;
  P.a0 = *(const float4*)(U + c0);  P.b0 = *(const float4*)(D + c0);
  P.e0 = *(const float4*)(BL + c0); P.f0 = *(const float4*)(HW + c0);
  P.g0 = *(const float4*)(HS + c0);
  int c1 = 128 + s * 2;
  P.a1 = *(const float2*)(U + c1);  P.b1 = *(const float2*)(D + c1);
  P.e1 = *(const float2*)(BL + c1); P.f1 = *(const float2*)(HW + c1);
  P.g1 = *(const float2*)(HS + c1);
  int c2 = 192 + s;
  P.a2 = U[c2]; P.b2 = D[c2]; P.e2 = BL[c2]; P.f2 = HW[c2]; P.g2 = HS[c2];
}

template<int C>
__device__ __forceinline__ void apply32(float& xv, float& logdet, int s, int nb_idx,
    const float (&u)[C], const float (&d)[C], const float (&bl)[C],
    const float (&hw)[C], const float (&hs)[C])
{
  float he[C], t[C], f[C];
#pragma unroll
  for (int i = 0; i < C; ++i) { he[i] = __expf(u[i] + d[i]); t[i] = he[i] * hs[i]; }
#pragma unroll
  for (int i = 0; i < C; ++i) f[i] = (bl[i] < xv) ? 1.0f : 0.0f;
  if (s == 0)  f[0]     = 1.0f;   // edge 0 always counted (clamp-low)
  if (s == 31) f[C - 1] = 0.0f;   // last edge never counted (clamp-high)
  // next lane's firsts; cross-group garbage only feeds forced-zero slot
  float fN  = bperm(nb_idx, f[0]);
  float heN = bperm(nb_idx, he[0]);
  float area = 0.0f, hl = 0.0f, hr = 0.0f, loc = 0.0f, hwm = 0.0f, pt = 0.0f;
#pragma unroll
  for (int i = 0; i < C; ++i) {
    float fnext  = (i < C - 1) ? f[i + 1]  : fN;
    float henext = (i < C - 1) ? he[i + 1] : heN;
    float mi = f[i] * (1.0f - fnext);   // one-hot at bin bi
    area += t[i];
    hl  += he[i] * mi;
    hr  += henext * mi;
    loc += bl[i] * mi;
    hwm += hw[i] * mi;
    pt  += t[i] * f[i];                 // inclusive trapezoid sum through bi
  }
  area = grp32_sum(area);
  hl  = grp32_sum(hl);
  hr  = grp32_sum(hr);
  loc = grp32_sum(loc);
  hwm = grp32_sum(hwm);
  pt  = grp32_sum(pt);
  float larea = __log2f(area);
  float invarea = __builtin_amdgcn_rcpf(area);
  float part = pt - hl * hwm;           // unnormalized cdf at left edge of bin
  float inw = 2.0f * hwm;
  float alpha = (xv - loc) * __builtin_amdgcn_rcpf(inw);
  float dh = hr - hl;
  xv = ((0.5f * dh * alpha + hl) * alpha * inw + part) * invarea;
  logdet += (__log2f(alpha * dh + hl) - larea) * 0.69314718055994531f;
}

__device__ __forceinline__ void compute_pt(const PtState& P, int s, int nb_idx,
                                           float* __restrict__ out)
{
  float xv = P.xv;
  float logdet = 0.0f;
  {
    float u[4]  = {P.a0.x, P.a0.y, P.a0.z, P.a0.w};
    float d[4]  = {P.b0.x, P.b0.y, P.b0.z, P.b0.w};
    float bl[4] = {P.e0.x, P.e0.y, P.e0.z, P.e0.w};
    float hw[4] = {P.f0.x, P.f0.y, P.f0.z, P.f0.w};
    float hs[4] = {P.g0.x, P.g0.y, P.g0.z, P.g0.w};
    apply32<4>(xv, logdet, s, nb_idx, u, d, bl, hw, hs);
  }
  {
    float u[2]  = {P.a1.x, P.a1.y};
    float d[2]  = {P.b1.x, P.b1.y};
    float bl[2] = {P.e1.x, P.e1.y};
    float hw[2] = {P.f1.x, P.f1.y};
    float hs[2] = {P.g1.x, P.g1.y};
    apply32<2>(xv, logdet, s, nb_idx, u, d, bl, hw, hs);
  }
  {
    float u[1]  = {P.a2};
    float d[1]  = {P.b2};
    float bl[1] = {P.e2};
    float hw[1] = {P.f2};
    float hs[1] = {P.g2};
    apply32<1>(xv, logdet, s, nb_idx, u, d, bl, hw, hs);
  }
  if (s == 0) {
    out[P.pid] = xv;
    out[NPOINTS + P.pid] = logdet;
  }
}

__global__ void __launch_bounds__(256, 4) spline_kernel(
    const float* __restrict__ x, const int* __restrict__ roi,
    const int* __restrict__ lix, const float* __restrict__ delta,
    const float* __restrict__ hemb,
    const float* __restrict__ wsBL, const float* __restrict__ wsHW,
    const float* __restrict__ wsHS, float* __restrict__ out)
{
  int tid  = (int)(blockIdx.x * blockDim.x + threadIdx.x);
  int wid  = tid >> 6;
  int lane = (int)(threadIdx.x & 63);
  int grp  = lane >> 5;            // 2 groups per wave
  int s    = lane & 31;            // 32-lane group, lanes <-> columns
  int base = wid * 4;              // 4 points per wave (2 pipelined pairs)
  int nb_idx = ((lane + 1) & 63) << 2;

  // issue BOTH pairs' load chains before any compute (2-deep pipeline)
  PtState A, B;
  load_pt(A, base + grp,     s, x, lix, roi, delta, hemb, wsBL, wsHW, wsHS);
  load_pt(B, base + 2 + grp, s, x, lix, roi, delta, hemb, wsBL, wsHW, wsHS);

  compute_pt(A, s, nb_idx, out);
  compute_pt(B, s, nb_idx, out);
}

// ---------- launch ----------

extern "C" void kernel_launch(void* const* d_in, const int* in_sizes, int n_in,
                              void* d_out, int out_size, void* d_ws, size_t ws_size,
                              hipStream_t stream) {
  const float* x     = (const float*)d_in[0];
  const int*   roi   = (const int*)  d_in[1];
  const int*   lix   = (const int*)  d_in[2];
  const float* delta = (const float*)d_in[3];
  const float* hemb  = (const float*)d_in[4];
  const float* wemb  = (const float*)d_in[5];

  float* wsBL = (float*)d_ws;                    // [500][224]
  float* wsHW = wsBL + (size_t)NREG * SUMH;      // [500][224]
  float* wsHS = wsHW + (size_t)NREG * SUMH;      // [500][224]

  region_kernel<<<NREG, 64, 0, stream>>>(roi, wemb, wsBL, wsHW, wsHS);
  spline_kernel<<<NPOINTS / 16, 256, 0, stream>>>(x, roi, lix, delta, hemb,
                                                  wsBL, wsHW, wsHS, (float*)d_out);
}